// Round 8
// baseline (516.304 us; speedup 1.0000x reference)
//
#include <hip/hip_runtime.h>
#include <math.h>

// AugmentPipe: flip -> affine(rot/scale/trans) bilinear-reflect sample ->
// brightness -> contrast -> saturation -> cutout(noise). One fused pass.
// B=64, C=3, H=W=512, float32 in/out.
//
// R9 -> R10. R2/R5/R8/R9 all pinned at 182-190us with different counter
// mixes; the shared cost is the fallback path: every rotated batch (half of
// all, angle ~ U(-pi,pi)) has ~35% of tiles failing the interior gate and
// paying R2's TA-serialized scattered gather (~72cy/instr, ~150K cy/CU).
// R10 removes the fallback ENTIRELY by staging in VIRTUAL (pre-reflect)
// coordinates: lerp symmetry makes taps (floor(v), floor(v)+1) with weight
// frac(v), each tap mapped through integer reflection
//   R(v) = v<0 ? -1-v : (v>511 ? 1023-v : v)
// EXACTLY equal to the reference reflect-then-floor-then-clamp (verified on
// ascending/descending pieces and both folds; virtual range [-211,722] =>
// one fold per side). Staging loads each virtual row/col from its reflected
// source: per thread 2 int reflects classify its 4 consecutive virtual cols
// as contiguous-ascending (dwordx4), contiguous-descending (dwordx4 +
// in-reg reverse -- also absorbs flip, same as R9), or fold-straddling
// (4 scalar dwords, ~1 thread/wave near edges). One uniform code path,
// no per-pixel reflect/clamps, no scattered gathers, uniform block times.
// Kept from R9: 128x16 strip (NT=8), reg-prefetch one tile ahead,
// lgkmcnt-only pipe_barrier, XCD swizzle, FSTRIDE 40, fmed3, 32-bit saddr.

constexpr int Bn = 64;
constexpr int Cn = 3;
constexpr int Hn = 512;
constexpr int Wn = 512;
constexpr float TRANSLATE_STD = 0.125f;
constexpr float SCALE_STD = 0.2f;
constexpr int CUT_H = 256; // int(512*0.5)
constexpr int CUT_W = 256;

constexpr int FW = 32;        // staged virtual box width (8 threads x 4 cols)
constexpr int FSTRIDE = 40;   // LDS row stride (160B, 16B-aligned rows)
constexpr int FH_MAX = 32;    // staged rows capacity (math bound 30)
constexpr int CH_LDS = FSTRIDE * FH_MAX;   // 1280 floats per channel
constexpr int NT = 8;         // tiles per block (128x16 strip)
constexpr uint32_t PLANE = 512u * 512u;

typedef float f4v __attribute__((ext_vector_type(4)));

// Integer reflect of a virtual tap index into [0,511]. Valid for
// v in [-512, 1022]; our range is [-211, 722].
__device__ __forceinline__ int refl(int v) {
    v = (v < 0) ? (-1 - v) : v;          // fold about -0.5
    return (v > 511) ? (1023 - v) : v;   // fold about 511.5
}

// Barrier that drains DS ops only; VMEM (stores, prefetch loads) stays in
// flight across it.
__device__ __forceinline__ void pipe_barrier() {
    asm volatile("s_waitcnt lgkmcnt(0)" ::: "memory");
    __builtin_amdgcn_s_barrier();
    __builtin_amdgcn_sched_barrier(0);
}

__global__ __launch_bounds__(256) void augment_kernel(
    const float* __restrict__ images,
    const float* __restrict__ u_angle,
    const float* __restrict__ u_scale,
    const float* __restrict__ u_trans,
    const float* __restrict__ u_bright,
    const float* __restrict__ u_contrast,
    const float* __restrict__ u_sat,
    const float* __restrict__ noise,
    const int* __restrict__ m_flip,
    const int* __restrict__ m_rot,
    const int* __restrict__ m_scale,
    const int* __restrict__ m_trans,
    const int* __restrict__ m_bright,
    const int* __restrict__ m_contrast,
    const int* __restrict__ m_sat,
    const int* __restrict__ m_cut,
    const int* __restrict__ y0p,
    const int* __restrict__ x0p,
    float* __restrict__ out)
{
    __shared__ __align__(16) float lds[Cn * CH_LDS];   // 15360 B -> 8 blk/CU

    // XCD swizzle: each XCD (lin%8) gets a contiguous 1024-block chunk =
    // 8 whole batches; strip-then-row order inside (R9-proven: FETCH -47%).
    const int lin = blockIdx.x + (blockIdx.y << 2) + (blockIdx.z << 7);
    const int swz = ((lin & 7) << 10) + (lin >> 3);
    const int sx0 = (swz & 3) << 7;            // strip origin x (0..384)
    const int y16 = (swz >> 2) & 31;           // tile-row
    const int b   = swz >> 7;                  // batch

    const int tx  = threadIdx.x;               // 0..15
    const int ty  = threadIdx.y;               // 0..15
    const int y   = (y16 << 4) + ty;

    // ---- Per-batch setup (amortized over 8 tiles).
    const float angle = (m_rot[b] > 0) ? (u_angle[b] * 2.0f - 1.0f) * 3.14159265358979323846f : 0.0f;
    const float sc    = (m_scale[b] > 0) ? (u_scale[b] * 2.0f - 1.0f) * SCALE_STD + 1.0f : 1.0f;
    const float tr    = (m_trans[b] > 0) ? (u_trans[b] * 2.0f - 1.0f) * TRANSLATE_STD : 0.0f;
    const float bb    = (m_bright[b] > 0) ? u_bright[b] * 0.2f : 0.0f;
    const float cc    = (m_contrast[b] > 0) ? u_contrast[b] + 0.5f : 1.0f;
    const float ss    = (m_sat[b] > 0) ? u_sat[b] * 2.0f : 1.0f;
    const bool  flip  = m_flip[b] > 0;
    const bool  docut = m_cut[b] > 0;
    const int   cy0   = y0p[b];
    const int   cx0   = x0p[b];

    float saf, caf;
    __sincosf(angle, &saf, &caf);

    // Incremental affine basis (validated R6/R8/R9).
    const float kk = sc * (512.0f / 511.0f);
    const float dxdx = caf * kk, dxdy = -saf * kk;
    const float dydx = saf * kk, dydy = caf * kk;
    const float xx_org = 256.0f * (sc * (saf - caf) + tr + 1.0f) - 0.5f;
    const float yy_org = 256.0f * (sc * (-saf - caf) + tr + 1.0f) - 0.5f;

    const float step_x = 16.0f * dxdx;
    const float step_y = 16.0f * dydx;

    float xxt = xx_org + (float)(sx0 + tx) * dxdx + (float)y * dxdy;
    float yyt = yy_org + (float)(sx0 + tx) * dydx + (float)y * dydy;

    const float fty = (float)(y16 << 4);
    float bx = xx_org + (float)sx0 * dxdx + fty * dxdy;   // rolling corner
    float by = yy_org + (float)sx0 * dydx + fty * dydy;
    const float sxx = 15.0f * dxdx, sxy = 15.0f * dxdy;
    const float syx = 15.0f * dydx, syy = 15.0f * dydy;
    const float min_dx = fminf(sxx, 0.0f) + fminf(sxy, 0.0f);
    const float min_dy = fminf(syx, 0.0f) + fminf(syy, 0.0f);
    const float max_dy = fmaxf(syx, 0.0f) + fmaxf(syy, 0.0f);

    const float* __restrict__ imgb = images + (size_t)b * (Cn * PLANE);
    float* __restrict__ outb       = out    + (size_t)b * (Cn * PLANE);
    const float* __restrict__ noib = noise  + (size_t)b * (Cn * PLANE);

    // Staging lane geometry: 32 virtual rows x 8 quad-columns (= 32 = FW).
    const int tid = ty * 16 + tx;
    const int sr  = tid >> 3;            // staged virtual row 0..31
    const int sq  = (tid & 7) << 2;      // virtual col offset 0,4,..,28

    const bool ycut = docut && (y >= cy0) && (y < cy0 + CUT_H);
    uint32_t opix = (uint32_t)y * 512u + (uint32_t)(sx0 + tx);

    // ---- Virtual box (NO gate, NO clamping: every tile is staged).
    int cx_lo, cy_lo, cfh;
    int nx_lo, ny_lo, nfh;
    auto mkbox = [&](float bxv, float byv, int& x_lo, int& y_lo, int& fh) {
        x_lo = (int)floorf(bxv + min_dx) - 1;
        y_lo = (int)floorf(byv + min_dy) - 1;
        fh   = min(((int)floorf(byv + max_dy) + 2) - y_lo + 1, FH_MAX);
    };

    // Prefetch registers (one tile's staged rows for this thread).
    f4v A{}, B{}, C{};
    bool rev = false;
    auto loadR = [&](int x_lo, int y_lo) {
        const uint32_t ro = (uint32_t)refl(y_lo + sr) * 512u;
        const int c0 = x_lo + sq;
        int S0 = refl(c0);     if (flip) S0 = 511 - S0;
        int S3 = refl(c0 + 3); if (flip) S3 = 511 - S3;
        const int d = S3 - S0;
        if (d == 3) {                       // contiguous ascending
            rev = false;
            __builtin_memcpy(&A, imgb + ro + S0, 16);
            __builtin_memcpy(&B, imgb + ro + S0 + PLANE, 16);
            __builtin_memcpy(&C, imgb + ro + S0 + 2 * PLANE, 16);
        } else if (d == -3) {               // contiguous descending (flip
            rev = true;                     // and/or reflect-descending)
            __builtin_memcpy(&A, imgb + ro + S3, 16);
            __builtin_memcpy(&B, imgb + ro + S3 + PLANE, 16);
            __builtin_memcpy(&C, imgb + ro + S3 + 2 * PLANE, 16);
        } else {                            // fold inside the quad (rare)
            rev = false;
            int S1 = refl(c0 + 1); if (flip) S1 = 511 - S1;
            int S2 = refl(c0 + 2); if (flip) S2 = 511 - S2;
            A = f4v{imgb[ro + S0], imgb[ro + S1], imgb[ro + S2], imgb[ro + S3]};
            const float* p1 = imgb + PLANE;
            B = f4v{p1[ro + S0], p1[ro + S1], p1[ro + S2], p1[ro + S3]};
            const float* p2 = imgb + 2 * PLANE;
            C = f4v{p2[ro + S0], p2[ro + S1], p2[ro + S2], p2[ro + S3]};
        }
    };
    auto writeR = [&]() {
        f4v a = A, b2 = B, c2 = C;
        if (rev) {
            a  = f4v{A.w, A.z, A.y, A.x};
            b2 = f4v{B.w, B.z, B.y, B.x};
            c2 = f4v{C.w, C.z, C.y, C.x};
        }
        float* d = &lds[sr * FSTRIDE + sq];
        *(f4v*)(d)              = a;
        *(f4v*)(d + CH_LDS)     = b2;
        *(f4v*)(d + 2 * CH_LDS) = c2;
    };

    // ---- Prologue: tile0 staged; tile1 loads in flight.
    mkbox(bx, by, cx_lo, cy_lo, cfh);
    if (sr < cfh) { loadR(cx_lo, cy_lo); writeR(); }   // auto counted vmcnt
    bx += step_x; by += step_y;
    mkbox(bx, by, nx_lo, ny_lo, nfh);
    if (sr < nfh) loadR(nx_lo, ny_lo);
    pipe_barrier();                        // publish tile0

    #pragma unroll 1
    for (int t = 0; t < NT; ++t) {
        // ---- Exact bilinear from LDS (virtual coords; no clamps/selects).
        const float fx = xxt - (float)cx_lo;
        const float fy = yyt - (float)cy_lo;
        const int xi = (int)fx;
        const int yi = (int)fy;
        const float wx = fx - (float)xi;
        const float wy = fy - (float)yi;
        const float* ph = &lds[yi * FSTRIDE + xi];

        float vals[Cn];
        #pragma unroll
        for (int c = 0; c < Cn; ++c) {
            const float v00 = ph[0], v01 = ph[1];
            const float v10 = ph[FSTRIDE], v11 = ph[FSTRIDE + 1];
            ph += CH_LDS;
            const float top = v00 + wx * (v01 - v00);
            const float bot = v10 + wx * (v11 - v10);
            float v = top + wy * (bot - top);
            v = __builtin_amdgcn_fmed3f(v + bb, -1.0f, 1.0f);  // brightness
            v = __builtin_amdgcn_fmed3f(v * cc, -1.0f, 1.0f);  // contrast
            vals[c] = v;
        }

        // ---- Saturation + cutout + store (stores fly across barriers).
        const float gray = (vals[0] + vals[1] + vals[2]) * (1.0f / 3.0f);
        const int xpix = sx0 + (t << 4) + tx;
        const bool cut = ycut && (xpix >= cx0) && (xpix < cx0 + CUT_W);
        #pragma unroll
        for (int c = 0; c < Cn; ++c) {
            float v = gray + ss * (vals[c] - gray);
            v = __builtin_amdgcn_fmed3f(v, -1.0f, 1.0f);
            if (cut) v = __builtin_nontemporal_load(&noib[opix + c * PLANE]);
            __builtin_nontemporal_store(v, &outb[opix + c * PLANE]);
        }
        opix += 16;
        xxt += step_x; yyt += step_y;

        if (t == NT - 1) break;

        pipe_barrier();                    // all reads of tile t done
        cx_lo = nx_lo; cy_lo = ny_lo; cfh = nfh;
        if (sr < cfh) writeR();            // counted-vmcnt wait on A,B,C
        bx += step_x; by += step_y;
        if (t + 2 < NT) {
            mkbox(bx, by, nx_lo, ny_lo, nfh);
            if (sr < nfh) loadR(nx_lo, ny_lo);   // hides under next compute
        } else {
            nfh = 0;
        }
        pipe_barrier();                    // publish tile t+1
    }
}

extern "C" void kernel_launch(void* const* d_in, const int* in_sizes, int n_in,
                              void* d_out, int out_size, void* d_ws, size_t ws_size,
                              hipStream_t stream) {
    const float* images     = (const float*)d_in[0];
    const float* u_angle    = (const float*)d_in[1];
    const float* u_scale    = (const float*)d_in[2];
    const float* u_trans    = (const float*)d_in[3];
    const float* u_bright   = (const float*)d_in[4];
    const float* u_contrast = (const float*)d_in[5];
    const float* u_sat      = (const float*)d_in[6];
    const float* noise      = (const float*)d_in[7];
    const int*   m_flip     = (const int*)d_in[8];
    const int*   m_rot      = (const int*)d_in[9];
    const int*   m_scale    = (const int*)d_in[10];
    const int*   m_trans    = (const int*)d_in[11];
    const int*   m_bright   = (const int*)d_in[12];
    const int*   m_contrast = (const int*)d_in[13];
    const int*   m_sat      = (const int*)d_in[14];
    const int*   m_cut      = (const int*)d_in[15];
    const int*   y0p        = (const int*)d_in[16];
    const int*   x0p        = (const int*)d_in[17];
    float* out = (float*)d_out;

    dim3 block(16, 16);
    dim3 grid(Wn / (16 * NT), Hn / 16, Bn);   // (4, 32, 64) = 8192 blocks
    augment_kernel<<<grid, block, 0, stream>>>(
        images, u_angle, u_scale, u_trans, u_bright, u_contrast, u_sat, noise,
        m_flip, m_rot, m_scale, m_trans, m_bright, m_contrast, m_sat, m_cut,
        y0p, x0p, out);
}